// Round 14
// baseline (250.223 us; speedup 1.0000x reference)
//
#include <hip/hip_runtime.h>
#include <cmath>

// ---------------- problem constants ----------------
constexpr int BATCH = 4096;
constexpr float EPSN = 1e-4f;

// d_out layout (floats): [new_stoch | new_deter | logit]
constexpr int OFF_STOCH = 0;
constexpr int OFF_DETER = BATCH * 512;
constexpr int OFF_LOGIT = OFF_DETER + BATCH * 2048;

typedef unsigned short ushort;
typedef __attribute__((ext_vector_type(4))) float f32x4;
typedef __attribute__((ext_vector_type(8))) short s16x8;
struct us4 { ushort x, y, z, w; };

// ---------------- ws layout (PROVEN 61.5 MiB budget — do not exceed) ----------------
constexpr size_t U_WHH = 0;                      // hid hi  [g] 256n x 1024k (NK=32)
constexpr size_t U_WHL = U_WHH + 2097152;
constexpr size_t U_WGH = U_WHL + 2097152;        // gru hi  [g*4+nc] 192n x 256k (NK=8)
constexpr size_t U_WGL = U_WGH + 1572864;
constexpr size_t U_WFH = U_WGL + 1572864;        // obs_fc0 hi 256n x 3072k (NK=96)
constexpr size_t U_WFL = U_WFH + 786432;
constexpr size_t U_WOH = U_WFL + 786432;         // obs_out hi 512n x 256k (NK=8)
constexpr size_t U_WOL = U_WOH + 131072;
constexpr size_t U_PEND = U_WOL + 131072;        // 9,175,040 ushorts
constexpr size_t F_XB = U_PEND / 2;              // xb: packed [4096][768h|768l] bf16
constexpr size_t F_XH = F_XB + 3145728;          // xh: f32 yh then packed [2048h|2048l]/row
constexpr size_t U_X0H = (F_XH + 6291456) * 2;   // transient in0_w 256n x 2048k (NK=64)
constexpr size_t U_X0L = U_X0H + 524288;
constexpr size_t U_X1H = U_X0L + 524288;         // in1_w 256n x 512k (NK=16)
constexpr size_t U_X1L = U_X1H + 131072;
constexpr size_t F_HB = F_XH + 4194304;          // hb packed [4096][256h|256l]

#define DINLINE __device__ __forceinline__

DINLINE float sigm(float x)  { return 1.0f / (1.0f + expf(-x)); }
DINLINE float siluf(float x) { return x / (1.0f + expf(-x)); }

DINLINE float4 ld4(const float* p) { return *reinterpret_cast<const float4*>(p); }
DINLINE void st4(float* p, float4 v) { *reinterpret_cast<float4*>(p) = v; }

DINLINE ushort f2bf(float x) {  // RNE f32->bf16 bits
  unsigned u = __float_as_uint(x);
  unsigned r = u + 0x7fffu + ((u >> 16) & 1u);
  return (ushort)(r >> 16);
}
DINLINE float bf2f(ushort h) { return __uint_as_float(((unsigned)h) << 16); }

DINLINE void cp16g(void* lds, const void* g) {
  __builtin_amdgcn_global_load_lds(
      (const __attribute__((address_space(1))) unsigned int*)g,
      (__attribute__((address_space(3))) unsigned int*)lds, 16, 0, 0);
}

DINLINE f32x4 mfma16(s16x8 a, s16x8 b, f32x4 c) {
  return __builtin_amdgcn_mfma_f32_16x16x32_bf16(a, b, c, 0, 0, 0);
}

// XOR-swizzled LDS byte address for [row][64B of k] bf16 tiles (validated round 6).
DINLINE int swz_addr(int row, int kb0) {
  return (row * 64 + kb0) ^ ((row & 7) << 4);
}
DINLINE void dec_swz(int D, int& row, int& kb) {
  int r2 = (D >> 8) & 1;
  int r0 = ((D >> 6) & 1) ^ r2;
  row = ((D >> 7) << 1) | r0;
  kb = (D & 48) ^ ((row & 3) << 4);
}

DINLINE void split2(float x, ushort& h, ushort& l) {
  h = f2bf(x);
  l = f2bf(x - bf2f(h));
}

DINLINE size_t frag_idx(int n, int k, int NK) {
  return ((size_t)((n >> 4) * NK + (k >> 5)) * 64 + ((k >> 3) & 3) * 16 + (n & 15)) * 8 + (k & 7);
}

DINLINE float4 rms_silu4(float v0, float v1, float v2, float v3, float4 s4) {
  float ss = v0 * v0 + v1 * v1 + v2 * v2 + v3 * v3;
#pragma unroll
  for (int off = 32; off; off >>= 1) ss += __shfl_xor(ss, off);
  float inv = 1.0f / sqrtf(ss * (1.0f / 256.0f) + EPSN);
  float4 o;
  o.x = siluf(v0 * inv * s4.x); o.y = siluf(v1 * inv * s4.y);
  o.z = siluf(v2 * inv * s4.z); o.w = siluf(v3 * inv * s4.w);
  return o;
}

// ---------------- kernel 1: weight prep (fragment-major, unchanged r11) ----------------
__global__ __launch_bounds__(256) void k_prep(
    const float* __restrict__ hk, const float* __restrict__ gk,
    const float* __restrict__ w0, const float* __restrict__ w1,
    const float* __restrict__ wf, const float* __restrict__ wo,
    ushort* __restrict__ wsU) {
  __shared__ float L[64 * 65];
  const int bid = blockIdx.x, tid = threadIdx.x;
  if (bid < 1792) {
    int t = bid * 256 + tid;
    if (t < 262144) {
      int o = t >> 10, i = t & 1023;
      const float* src = hk + (size_t)t * 8;
      float4 v0 = ld4(src), v1 = ld4(src + 4);
      float vv[8] = {v0.x, v0.y, v0.z, v0.w, v1.x, v1.y, v1.z, v1.w};
      size_t fi = frag_idx(o, i, 32);
#pragma unroll
      for (int g2 = 0; g2 < 8; ++g2) {
        ushort h, l; split2(vv[g2], h, l);
        wsU[U_WHH + (size_t)g2 * 262144 + fi] = h;
        wsU[U_WHL + (size_t)g2 * 262144 + fi] = l;
      }
    } else {
      int e = t - 262144;
      int o = e >> 8, i = e & 255;
      const float* src = gk + (size_t)e * 8;
      float4 v0 = ld4(src), v1 = ld4(src + 4);
      float vv[8] = {v0.x, v0.y, v0.z, v0.w, v1.x, v1.y, v1.z, v1.w};
      int gate = o >> 8, nc = (o >> 6) & 3, srow = gate * 64 + (o & 63);
      size_t fi = frag_idx(srow, i, 8);
#pragma unroll
      for (int g2 = 0; g2 < 8; ++g2) {
        ushort h, l; split2(vv[g2], h, l);
        size_t pb = (size_t)(g2 * 4 + nc) * 49152;
        wsU[U_WGH + pb + fi] = h;
        wsU[U_WGL + pb + fi] = l;
      }
    }
    return;
  }
  int t = bid - 1792;
  const float* src; ushort* dh; ushort* dl; int K, N;
  if (t < 128)      { src = w0; dh = wsU + U_X0H; dl = wsU + U_X0L; K = 2048; N = 256; }
  else if (t < 160) { t -= 128; src = w1; dh = wsU + U_X1H; dl = wsU + U_X1L; K = 512;  N = 256; }
  else if (t < 352) { t -= 160; src = wf; dh = wsU + U_WFH; dl = wsU + U_WFL; K = 3072; N = 256; }
  else              { t -= 352; src = wo; dh = wsU + U_WOH; dl = wsU + U_WOL; K = 256;  N = 512; }
  const int NK = K / 32;
  const int ntiles = N / 64;
  const int k0 = (t / ntiles) * 64, n0 = (t % ntiles) * 64;
#pragma unroll
  for (int q = 0; q < 4; ++q) {
    int row = q * 16 + (tid >> 4), col = (tid & 15) * 4;
    float4 v = ld4(src + (size_t)(k0 + row) * N + n0 + col);
    L[row * 65 + col]     = v.x;
    L[row * 65 + col + 1] = v.y;
    L[row * 65 + col + 2] = v.z;
    L[row * 65 + col + 3] = v.w;
  }
  __syncthreads();
  const int nl = tid >> 2, kc = (tid & 3) * 16;
  const int ng = n0 + nl;
  s16x8 h0, h1, l0v, l1v;
#pragma unroll
  for (int j = 0; j < 16; ++j) {
    ushort h, l; split2(L[(kc + j) * 65 + nl], h, l);
    if (j < 8) { h0[j] = (short)h; l0v[j] = (short)l; }
    else       { h1[j - 8] = (short)h; l1v[j - 8] = (short)l; }
  }
  size_t fa = frag_idx(ng, k0 + kc, NK);
  size_t fb = frag_idx(ng, k0 + kc + 8, NK);
  *(s16x8*)(dh + fa) = h0;
  *(s16x8*)(dh + fb) = h1;
  *(s16x8*)(dl + fa) = l0v;
  *(s16x8*)(dl + fb) = l1v;
}

// ---------------- unified MFMA GEMM: A via LDS, B from L2 at loop top (r11 placement) ----------------
__global__ __launch_bounds__(512) void k_gemm256(
    int mode,
    const float* __restrict__ deter, const float* __restrict__ stoch,
    const float* __restrict__ newdet, const float* __restrict__ embed,
    const ushort* __restrict__ wsU, float* __restrict__ part) {
  __shared__ ushort Ah[2][64 * 32], Al[2][64 * 32];
  const int tid = threadIdx.x, lane = tid & 63, wv = tid >> 6;
  const int wr = wv >> 2, wc = wv & 3;
  const int bid = blockIdx.x;
  constexpr size_t PL0 = (size_t)4096 * 512;

  const float* A0; const float* A1 = nullptr;
  int lda0, lda1 = 0, ksw = 1 << 30;
  const ushort* wFh; const ushort* wFl;
  int NKt, kch0, kbase, KT, m0, dstride, dcol;
  float* dst;

  if (mode == 0) {
    if (bid < 256) {
      int ks = bid & 3; m0 = (bid >> 2) * 64; kbase = ks * 512; KT = 16;
      A0 = deter; lda0 = 2048;
      wFh = wsU + U_X0H; wFl = wsU + U_X0L; NKt = 64; kch0 = ks * 16;
      dst = part + (size_t)(ks >> 1) * PL0; dstride = 512; dcol = (ks & 1) * 256;
    } else {
      int b = bid - 256; int ks = b & 1; m0 = (b >> 1) * 64; kbase = ks * 256; KT = 8;
      A0 = stoch; lda0 = 512;
      wFh = wsU + U_X1H; wFl = wsU + U_X1L; NKt = 16; kch0 = ks * 8;
      dst = part + 2 * PL0; dstride = 512; dcol = ks * 256;
    }
  } else {
    int ks = bid & 3; m0 = (bid >> 2) * 64; kbase = ks * 768; KT = 24;
    A0 = newdet; lda0 = 2048; A1 = embed; lda1 = 1024; ksw = 2048;
    wFh = wsU + U_WFH; wFl = wsU + U_WFL; NKt = 96; kch0 = ks * 24;
    dst = part + (size_t)ks * 4096 * 256; dstride = 256; dcol = 0;
  }

  const int arow = tid >> 2, akq = (tid & 3) * 8;
  const int abyte = swz_addr(arow, (tid & 3) * 16);
  float av[8];

  const f32x4 z4 = {0.f, 0.f, 0.f, 0.f};
  f32x4 acc[2][4];
#pragma unroll
  for (int i = 0; i < 2; ++i)
#pragma unroll
    for (int j = 0; j < 4; ++j) acc[i][j] = z4;

#define U_LOADA(kt) \
  if (tid < 256) { \
    int kg = kbase + (kt) * 32 + akq; \
    const float* p = (kg < ksw) ? A0 + (size_t)(m0 + arow) * lda0 + kg \
                                : A1 + (size_t)(m0 + arow) * lda1 + (kg - ksw); \
    float4 u_ = ld4(p), w_ = ld4(p + 4); \
    av[0] = u_.x; av[1] = u_.y; av[2] = u_.z; av[3] = u_.w; \
    av[4] = w_.x; av[5] = w_.y; av[6] = w_.z; av[7] = w_.w; \
  }
#define U_WRITEA(buf) \
  if (tid < 256) { \
    s16x8 h8, l8; \
    _Pragma("unroll") \
    for (int j = 0; j < 8; ++j) { \
      ushort h_, l_; split2(av[j], h_, l_); \
      h8[j] = (short)h_; l8[j] = (short)l_; \
    } \
    *(s16x8*)((char*)Ah[buf] + abyte) = h8; \
    *(s16x8*)((char*)Al[buf] + abyte) = l8; \
  }

  U_LOADA(0);
  U_WRITEA(0);
  __syncthreads();
  int cur = 0;
  for (int t = 0; t < KT; ++t) {
    if (t + 1 < KT) { U_LOADA(t + 1); }
    s16x8 bh[4], bl[4];
#pragma unroll
    for (int nf = 0; nf < 4; ++nf) {
      size_t fo = ((size_t)((wc * 4 + nf) * NKt + kch0 + t) * 64 + lane) * 8;
      bh[nf] = *(const s16x8*)(wFh + fo);
      bl[nf] = *(const s16x8*)(wFl + fo);
    }
    const int k16 = (lane >> 4) * 16;
    s16x8 afh[2], afl[2];
#pragma unroll
    for (int mf = 0; mf < 2; ++mf) {
      int by = swz_addr(wr * 32 + mf * 16 + (lane & 15), k16);
      afh[mf] = *(const s16x8*)((const char*)Ah[cur] + by);
      afl[mf] = *(const s16x8*)((const char*)Al[cur] + by);
    }
#pragma unroll
    for (int nf = 0; nf < 4; ++nf) {
#pragma unroll
      for (int mf = 0; mf < 2; ++mf) {
        acc[mf][nf] = mfma16(afh[mf], bh[nf], acc[mf][nf]);
        acc[mf][nf] = mfma16(afh[mf], bl[nf], acc[mf][nf]);
        acc[mf][nf] = mfma16(afl[mf], bh[nf], acc[mf][nf]);
      }
    }
    if (t + 1 < KT) { U_WRITEA(cur ^ 1); }
    __syncthreads();
    cur ^= 1;
  }
#undef U_LOADA
#undef U_WRITEA
#pragma unroll
  for (int mf = 0; mf < 2; ++mf) {
    int rbase = m0 + wr * 32 + mf * 16 + ((lane >> 4) << 2);
#pragma unroll
    for (int nf = 0; nf < 4; ++nf) {
      int col = dcol + wc * 64 + nf * 16 + (lane & 15);
#pragma unroll
      for (int r = 0; r < 4; ++r)
        dst[(size_t)(rbase + r) * dstride + col] = acc[mf][nf][r];
    }
  }
}

// ---------------- x2: K=17 projection, 256 blocks x 256 threads ----------------
__global__ __launch_bounds__(256) void k_x2(
    const float* __restrict__ action, const float* __restrict__ w2,
    const float* __restrict__ b2, const float* __restrict__ s2,
    ushort* __restrict__ xbp) {
  __shared__ float W2s[17 * 256];
  __shared__ float A2s[16 * 20];
  const int tid = threadIdx.x, tx = tid & 63, wv = tid >> 6;
  const int m0 = blockIdx.x * 16;
  for (int e = tid; e < 17 * 256; e += 256) W2s[e] = w2[e];
  for (int e = tid; e < 272; e += 256) {
    int r = e / 17, c = e % 17;
    float a = action[(size_t)(m0 + r) * 17 + c];
    float m = fabsf(a);
    A2s[r * 20 + c] = a / (m > 1.f ? m : 1.f);
  }
  __syncthreads();
  float4 acc2[4];
#pragma unroll
  for (int r = 0; r < 4; ++r) acc2[r] = make_float4(0.f, 0.f, 0.f, 0.f);
#pragma unroll
  for (int k = 0; k < 17; ++k) {
    float4 w4 = ld4(W2s + k * 256 + tx * 4);
#pragma unroll
    for (int r = 0; r < 4; ++r) {
      float av = A2s[(wv * 4 + r) * 20 + k];
      acc2[r].x = fmaf(av, w4.x, acc2[r].x);
      acc2[r].y = fmaf(av, w4.y, acc2[r].y);
      acc2[r].z = fmaf(av, w4.z, acc2[r].z);
      acc2[r].w = fmaf(av, w4.w, acc2[r].w);
    }
  }
  float4 b4 = ld4(b2 + tx * 4);
  float4 s4 = ld4(s2 + tx * 4);
#pragma unroll
  for (int r = 0; r < 4; ++r) {
    float4 o = rms_silu4(acc2[r].x + b4.x, acc2[r].y + b4.y,
                         acc2[r].z + b4.z, acc2[r].w + b4.w, s4);
    us4 h4, l4;
    split2(o.x, h4.x, l4.x); split2(o.y, h4.y, l4.y);
    split2(o.z, h4.z, l4.z); split2(o.w, h4.w, l4.w);
    size_t rb = (size_t)(m0 + wv * 4 + r) * 1536;
    *(us4*)(xbp + rb + 512 + tx * 4) = h4;
    *(us4*)(xbp + rb + 768 + 512 + tx * 4) = l4;
  }
}

// ---------------- combine: x0 | x1 + bias + rmsnorm + silu -> packed xb ----------------
__global__ __launch_bounds__(256) void k_comb_in(
    const float* __restrict__ part,
    const float* __restrict__ b0, const float* __restrict__ s0,
    const float* __restrict__ b1, const float* __restrict__ s1,
    ushort* __restrict__ xbp) {
  const int tid = threadIdx.x, tx = tid & 63, wv = tid >> 6;
  const size_t row = blockIdx.x * 2 + (wv >> 1);
  const int half = wv & 1;
  constexpr size_t PL = (size_t)4096 * 512;
  float4 v = make_float4(0.f, 0.f, 0.f, 0.f);
  if (half == 0) {
#pragma unroll
    for (int p = 0; p < 2; ++p) {
      const float* s = part + p * PL + row * 512 + tx * 4;
      float4 a = ld4(s), b = ld4(s + 256);
      v.x += a.x + b.x; v.y += a.y + b.y; v.z += a.z + b.z; v.w += a.w + b.w;
    }
  } else {
    const float* s = part + 2 * PL + row * 512 + tx * 4;
    float4 a = ld4(s), b = ld4(s + 256);
    v.x = a.x + b.x; v.y = a.y + b.y; v.z = a.z + b.z; v.w = a.w + b.w;
  }
  const float* bp = half ? b1 : b0;
  const float* sp = half ? s1 : s0;
  float4 b4 = ld4(bp + tx * 4);
  float4 s4 = ld4(sp + tx * 4);
  float4 o = rms_silu4(v.x + b4.x, v.y + b4.y, v.z + b4.z, v.w + b4.w, s4);
  us4 h4, l4;
  split2(o.x, h4.x, l4.x); split2(o.y, h4.y, l4.y);
  split2(o.z, h4.z, l4.z); split2(o.w, h4.w, l4.w);
  *(us4*)(xbp + row * 1536 + half * 256 + tx * 4) = h4;
  *(us4*)(xbp + row * 1536 + 768 + half * 256 + tx * 4) = l4;
}

// ---------------- combine p=4 (obsfc0) -> packed hb ----------------
__global__ __launch_bounds__(256) void k_comb4(
    const float* __restrict__ part, const float* __restrict__ bias,
    const float* __restrict__ scale, ushort* __restrict__ hbp) {
  const int tid = threadIdx.x, tx = tid & 63, wv = tid >> 6;
  const size_t row = blockIdx.x * 4 + wv;
  float4 v = make_float4(0.f, 0.f, 0.f, 0.f);
#pragma unroll
  for (int ks = 0; ks < 4; ++ks) {
    float4 t = ld4(part + (size_t)ks * 4096 * 256 + row * 256 + tx * 4);
    v.x += t.x; v.y += t.y; v.z += t.z; v.w += t.w;
  }
  float4 b4 = ld4(bias + tx * 4);
  float4 s4 = ld4(scale + tx * 4);
  float4 o = rms_silu4(v.x + b4.x, v.y + b4.y, v.z + b4.z, v.w + b4.w, s4);
  us4 h4, l4;
  split2(o.x, h4.x, l4.x); split2(o.y, h4.y, l4.y);
  split2(o.z, h4.z, l4.z); split2(o.w, h4.w, l4.w);
  *(us4*)(hbp + row * 512 + tx * 4) = h4;
  *(us4*)(hbp + row * 512 + 256 + tx * 4) = l4;
}

// ---------------- hid0: A LDS, B from L2 at loop top ----------------
__global__ __launch_bounds__(512) void k_hid0m(
    const float* __restrict__ deter, const ushort* __restrict__ xbp,
    const ushort* __restrict__ wsU,
    const float* __restrict__ hbias, float* __restrict__ yh) {
  __shared__ ushort Ah[2][64 * 32], Al[2][64 * 32];
  const int tid = threadIdx.x, lane = tid & 63, wv = tid >> 6;
  const int wr = wv >> 2, wc = wv & 3;
  const int g = blockIdx.x & 7;
  const int m0 = (int)(blockIdx.x >> 3) * 64;

  const ushort* whFh = wsU + U_WHH + (size_t)g * 262144;
  const ushort* whFl = wsU + U_WHL + (size_t)g * 262144;
  const char* xbB = (const char*)xbp;

  const int arow = tid >> 2, akq = (tid & 3) * 8;
  const int abyte = swz_addr(arow, (tid & 3) * 16);
  int an0, akb;
  dec_swz(tid * 16, an0, akb);
  float av[8];

  const f32x4 z4 = {0.f, 0.f, 0.f, 0.f};
  f32x4 acc[2][4];
#pragma unroll
  for (int i = 0; i < 2; ++i)
#pragma unroll
    for (int j = 0; j < 4; ++j) acc[i][j] = z4;

#define H_LOADA_DET(kt) \
  if (tid < 256) { \
    const float* p = deter + (size_t)(m0 + arow) * 2048 + g * 256 + (kt) * 32 + akq; \
    float4 u_ = ld4(p), w_ = ld4(p + 4); \
    av[0] = u_.x; av[1] = u_.y; av[2] = u_.z; av[3] = u_.w; \
    av[4] = w_.x; av[5] = w_.y; av[6] = w_.z; av[7] = w_.w; \
  }
#define H_WRITEA(buf) \
  if (tid < 256) { \
    s16x8 h8, l8; \
    _Pragma("unroll") \
    for (int j = 0; j < 8; ++j) { \
      ushort h_, l_; split2(av[j], h_, l_); \
      h8[j] = (short)h_; l8[j] = (short)l_; \
    } \
    *(s16x8*)((char*)Ah[buf] + abyte) = h8; \
    *(s16x8*)((char*)Al[buf] + abyte) = l8; \
  }
#define H_ISSUEA(buf, kt) \
  if (tid < 256) { \
    size_t rb = (size_t)(m0 + an0) * 3072; \
    int co = ((kt) * 32 - 256) * 2 + akb; \
    cp16g((char*)Ah[buf] + tid * 16, xbB + rb + co); \
    cp16g((char*)Al[buf] + tid * 16, xbB + rb + 1536 + co); \
  }

  H_LOADA_DET(0);
  H_WRITEA(0);
  __syncthreads();
  int cur = 0;
  for (int t = 0; t < 32; ++t) {
    const bool pf = (t + 1 < 32);
    const bool det = (t + 1 < 8);
    if (pf) {
      if (det) { H_LOADA_DET(t + 1); }
      else     { H_ISSUEA(cur ^ 1, t + 1); }
    }
    s16x8 bh[4], bl[4];
#pragma unroll
    for (int nf = 0; nf < 4; ++nf) {
      size_t fo = ((size_t)((wc * 4 + nf) * 32 + t) * 64 + lane) * 8;
      bh[nf] = *(const s16x8*)(whFh + fo);
      bl[nf] = *(const s16x8*)(whFl + fo);
    }
    const int k16 = (lane >> 4) * 16;
    s16x8 afh[2], afl[2];
#pragma unroll
    for (int mf = 0; mf < 2; ++mf) {
      int by = swz_addr(wr * 32 + mf * 16 + (lane & 15), k16);
      afh[mf] = *(const s16x8*)((const char*)Ah[cur] + by);
      afl[mf] = *(const s16x8*)((const char*)Al[cur] + by);
    }
#pragma unroll
    for (int nf = 0; nf < 4; ++nf) {
#pragma unroll
      for (int mf = 0; mf < 2; ++mf) {
        acc[mf][nf] = mfma16(afh[mf], bh[nf], acc[mf][nf]);
        acc[mf][nf] = mfma16(afh[mf], bl[nf], acc[mf][nf]);
        acc[mf][nf] = mfma16(afl[mf], bh[nf], acc[mf][nf]);
      }
    }
    if (pf && det) { H_WRITEA(cur ^ 1); }
    __syncthreads();
    cur ^= 1;
  }
#undef H_LOADA_DET
#undef H_WRITEA
#undef H_ISSUEA
#pragma unroll
  for (int mf = 0; mf < 2; ++mf) {
    int rbase = m0 + wr * 32 + mf * 16 + ((lane >> 4) << 2);
#pragma unroll
    for (int nf = 0; nf < 4; ++nf) {
      int col = wc * 64 + nf * 16 + (lane & 15);
      float b = hbias[g * 256 + col];
#pragma unroll
      for (int r = 0; r < 4; ++r)
        yh[(size_t)(rbase + r) * 2048 + g * 256 + col] = acc[mf][nf][r] + b;
    }
  }
}

// ---------------- rmsnorm(2048)+silu -> in-place packed [2048h|2048l] bf16 ----------------
__global__ __launch_bounds__(256) void k_rmsnorm2048(
    float* __restrict__ xh, const float* __restrict__ scale) {
  const int b = blockIdx.x, tid = threadIdx.x;
  float* row = xh + (size_t)b * 2048;
  float4 v0 = ld4(row + tid * 8);
  float4 v1 = ld4(row + tid * 8 + 4);
  float ss = v0.x * v0.x + v0.y * v0.y + v0.z * v0.z + v0.w * v0.w +
             v1.x * v1.x + v1.y * v1.y + v1.z * v1.z + v1.w * v1.w;
#pragma unroll
  for (int off = 32; off; off >>= 1) ss += __shfl_xor(ss, off);
  __shared__ float wsum[4];
  if ((tid & 63) == 0) wsum[tid >> 6] = ss;
  __syncthreads();
  float tot = wsum[0] + wsum[1] + wsum[2] + wsum[3];
  float inv = 1.0f / sqrtf(tot * (1.0f / 2048.0f) + EPSN);
  float4 sc0 = ld4(scale + tid * 8);
  float4 sc1 = ld4(scale + tid * 8 + 4);
  float o[8];
  o[0] = siluf(v0.x * inv * sc0.x); o[1] = siluf(v0.y * inv * sc0.y);
  o[2] = siluf(v0.z * inv * sc0.z); o[3] = siluf(v0.w * inv * sc0.w);
  o[4] = siluf(v1.x * inv * sc1.x); o[5] = siluf(v1.y * inv * sc1.y);
  o[6] = siluf(v1.z * inv * sc1.z); o[7] = siluf(v1.w * inv * sc1.w);
  s16x8 h8, l8;
#pragma unroll
  for (int j = 0; j < 8; ++j) {
    ushort h, l; split2(o[j], h, l);
    h8[j] = (short)h; l8[j] = (short)l;
  }
  ushort* rp = (ushort*)row;
  *(s16x8*)(rp + tid * 8) = h8;
  *(s16x8*)(rp + 2048 + tid * 8) = l8;
}

// ---------------- gru: BM=64, stage ALL A once, barrier-free main loop ----------------
// grid: g(8) x nc(4) x m(64) = 2048 blocks. LDS: Ah[8][64*32] + Al = 64KB.
__global__ __launch_bounds__(512) void k_grum(
    const ushort* __restrict__ xhp, const ushort* __restrict__ wsU,
    const float* __restrict__ gb, const float* __restrict__ deter,
    float* __restrict__ newdet) {
  __shared__ ushort Ah[8][64 * 32], Al[8][64 * 32];   // 32KB + 32KB
  const int tid = threadIdx.x, lane = tid & 63, wv = tid >> 6;
  const int wr = wv >> 2, wc = wv & 3;
  const int g = blockIdx.x & 7;
  const int nc = (int)(blockIdx.x >> 3) & 3;
  const int m0 = (int)(blockIdx.x >> 5) * 64;

  const ushort* wgFh = wsU + U_WGH + (size_t)(g * 4 + nc) * 49152;
  const ushort* wgFl = wsU + U_WGL + (size_t)(g * 4 + nc) * 49152;
  const char* xhB = (const char*)xhp;

  // stage the whole 64x256 A tile (hi+lo), 4 rounds x 512 threads x 16B per plane
#pragma unroll
  for (int q = 0; q < 4; ++q) {
    int lin = q * 8192 + tid * 16;      // byte offset into Ah (32KB)
    int chunk = lin >> 12;              // 4KB per k-chunk of 32
    int within = lin & 4095;
    int row, kb;
    dec_swz(within, row, kb);
    size_t src = (size_t)(m0 + row) * 8192 + (size_t)(g * 256 + chunk * 32) * 2 + kb;
    cp16g((char*)Ah + lin, xhB + src);
    cp16g((char*)Al + lin, xhB + src + 4096);
  }
  __syncthreads();   // ONE barrier; main loop below is barrier-free

  const f32x4 z4 = {0.f, 0.f, 0.f, 0.f};
  f32x4 acc[2][3];
#pragma unroll
  for (int i = 0; i < 2; ++i)
#pragma unroll
    for (int j = 0; j < 3; ++j) acc[i][j] = z4;

#pragma unroll
  for (int t = 0; t < 8; ++t) {
    s16x8 bh[3], bl[3];
#pragma unroll
    for (int gt = 0; gt < 3; ++gt) {
      size_t fo = ((size_t)((gt * 4 + wc) * 8 + t) * 64 + lane) * 8;
      bh[gt] = *(const s16x8*)(wgFh + fo);
      bl[gt] = *(const s16x8*)(wgFl + fo);
    }
    const int k16 = (lane >> 4) * 16;
    s16x8 afh[2], afl[2];
#pragma unroll
    for (int mf = 0; mf < 2; ++mf) {
      int by = swz_addr(wr * 32 + mf * 16 + (lane & 15), k16);
      afh[mf] = *(const s16x8*)((const char*)Ah[t] + by);
      afl[mf] = *(const s16x8*)((const char*)Al[t] + by);
    }
#pragma unroll
    for (int gt = 0; gt < 3; ++gt) {
#pragma unroll
      for (int mf = 0; mf < 2; ++mf) {
        acc[mf][gt] = mfma16(afh[mf], bh[gt], acc[mf][gt]);
        acc[mf][gt] = mfma16(afh[mf], bl[gt], acc[mf][gt]);
        acc[mf][gt] = mfma16(afl[mf], bh[gt], acc[mf][gt]);
      }
    }
  }
  const int col = nc * 64 + wc * 16 + (lane & 15);
  const float br = gb[g * 768 + col];
  const float bc = gb[g * 768 + 256 + col];
  const float bu = gb[g * 768 + 512 + col];
#pragma unroll
  for (int mf = 0; mf < 2; ++mf) {
    int rbase = m0 + wr * 32 + mf * 16 + ((lane >> 4) << 2);
#pragma unroll
    for (int r = 0; r < 4; ++r) {
      int row = rbase + r;
      float rr = sigm(acc[mf][0][r] + br);
      float cc = acc[mf][1][r] + bc;
      float uu = sigm(acc[mf][2][r] + bu - 1.0f);
      float d = deter[(size_t)row * 2048 + g * 256 + col];
      newdet[(size_t)row * 2048 + g * 256 + col] =
          uu * tanhf(rr * cc) + (1.0f - uu) * d;
    }
  }
}

// ---------------- obs_out: A cp16, B from L2 at loop top ----------------
__global__ __launch_bounds__(512) void k_obsoutm(
    const ushort* __restrict__ hbp, const ushort* __restrict__ wsU,
    const float* __restrict__ ob, float* __restrict__ logit) {
  __shared__ ushort Ah[2][64 * 32], Al[2][64 * 32];
  const int tid = threadIdx.x, lane = tid & 63, wv = tid >> 6;
  const int wr = wv >> 2, wc = wv & 3;
  const int half = blockIdx.x & 1;
  const int m0 = (int)(blockIdx.x >> 1) * 64;

  const ushort* woFh = wsU + U_WOH;
  const ushort* woFl = wsU + U_WOL;
  const char* hbB = (const char*)hbp;
  int an0, akb;
  dec_swz(tid * 16, an0, akb);

  const f32x4 z4 = {0.f, 0.f, 0.f, 0.f};
  f32x4 acc[2][4];
#pragma unroll
  for (int i = 0; i < 2; ++i)
#pragma unroll
    for (int j = 0; j < 4; ++j) acc[i][j] = z4;

#define O_ISSUEA(buf, kt) \
  if (tid < 256) { \
    size_t rb = (size_t)(m0 + an0) * 1024; \
    int co = (kt) * 64 + akb; \
    cp16g((char*)Ah[buf] + tid * 16, hbB + rb + co); \
    cp16g((char*)Al[buf] + tid * 16, hbB + rb + 512 + co); \
  }

  O_ISSUEA(0, 0);
  __syncthreads();
  int cur = 0;
  for (int t = 0; t < 8; ++t) {
    if (t + 1 < 8) { O_ISSUEA(cur ^ 1, t + 1); }
    s16x8 bh[4], bl[4];
#pragma unroll
    for (int nf = 0; nf < 4; ++nf) {
      size_t fo = ((size_t)((half * 16 + wc * 4 + nf) * 8 + t) * 64 + lane) * 8;
      bh[nf] = *(const s16x8*)(woFh + fo);
      bl[nf] = *(const s16x8*)(woFl + fo);
    }
    const int k16 = (lane >> 4) * 16;
    s16x8 afh[2], afl[2];
#pragma unroll
    for (int mf = 0; mf < 2; ++mf) {
      int by = swz_addr(wr * 32 + mf * 16 + (lane & 15), k16);
      afh[mf] = *(const s16x8*)((const char*)Ah[cur] + by);
      afl[mf] = *(const s16x8*)((const char*)Al[cur] + by);
    }
#pragma unroll
    for (int nf = 0; nf < 4; ++nf) {
#pragma unroll
      for (int mf = 0; mf < 2; ++mf) {
        acc[mf][nf] = mfma16(afh[mf], bh[nf], acc[mf][nf]);
        acc[mf][nf] = mfma16(afh[mf], bl[nf], acc[mf][nf]);
        acc[mf][nf] = mfma16(afl[mf], bh[nf], acc[mf][nf]);
      }
    }
    __syncthreads();
    cur ^= 1;
  }
#undef O_ISSUEA
#pragma unroll
  for (int mf = 0; mf < 2; ++mf) {
    int rbase = m0 + wr * 32 + mf * 16 + ((lane >> 4) << 2);
#pragma unroll
    for (int nf = 0; nf < 4; ++nf) {
      int col = half * 256 + wc * 64 + nf * 16 + (lane & 15);
      float b = ob[col];
#pragma unroll
      for (int r = 0; r < 4; ++r)
        logit[(size_t)(rbase + r) * 512 + col] = acc[mf][nf][r] + b;
    }
  }
}

// ---------------- argmax -> one-hot (first-index ties) ----------------
__global__ __launch_bounds__(256) void k_argmax(
    const float* __restrict__ logit, float* __restrict__ stoch_out) {
  const size_t row = blockIdx.x * 4 + (threadIdx.x >> 6);
  const int lane = threadIdx.x & 63;
  const float* lp = logit + row * 512 + lane * 8;
  float4 a = ld4(lp), b = ld4(lp + 4);
  float v[8] = {a.x, a.y, a.z, a.w, b.x, b.y, b.z, b.w};
  float bv = v[0]; int bi = 0;
#pragma unroll
  for (int j = 1; j < 8; ++j)
    if (v[j] > bv) { bv = v[j]; bi = j; }
  bi += lane * 8;
  float pv = __shfl_xor(bv, 1);
  int   pi = __shfl_xor(bi, 1);
  if (pv > bv || (pv == bv && pi < bi)) { bv = pv; bi = pi; }
  float4 o0, o1;
  int base = lane * 8;
  o0.x = (bi == base + 0) ? 1.f : 0.f;
  o0.y = (bi == base + 1) ? 1.f : 0.f;
  o0.z = (bi == base + 2) ? 1.f : 0.f;
  o0.w = (bi == base + 3) ? 1.f : 0.f;
  o1.x = (bi == base + 4) ? 1.f : 0.f;
  o1.y = (bi == base + 5) ? 1.f : 0.f;
  o1.z = (bi == base + 6) ? 1.f : 0.f;
  o1.w = (bi == base + 7) ? 1.f : 0.f;
  st4(stoch_out + row * 512 + base, o0);
  st4(stoch_out + row * 512 + base + 4, o1);
}

// ---------------- launcher ----------------
extern "C" void kernel_launch(void* const* d_in, const int* in_sizes, int n_in,
                              void* d_out, int out_size, void* d_ws, size_t ws_size,
                              hipStream_t stream) {
  (void)in_sizes; (void)n_in; (void)out_size; (void)ws_size;
  const float* stoch      = (const float*)d_in[0];
  const float* deter      = (const float*)d_in[1];
  const float* action     = (const float*)d_in[2];
  const float* embed      = (const float*)d_in[3];
  const float* in0_w      = (const float*)d_in[4];
  const float* in0_b      = (const float*)d_in[5];
  const float* n0_s       = (const float*)d_in[6];
  const float* in1_w      = (const float*)d_in[7];
  const float* in1_b      = (const float*)d_in[8];
  const float* n1_s       = (const float*)d_in[9];
  const float* in2_w      = (const float*)d_in[10];
  const float* in2_b      = (const float*)d_in[11];
  const float* n2_s       = (const float*)d_in[12];
  const float* hid0_k     = (const float*)d_in[13];
  const float* hid0_b     = (const float*)d_in[14];
  const float* hidn_s     = (const float*)d_in[15];
  const float* gru_k      = (const float*)d_in[16];
  const float* gru_b      = (const float*)d_in[17];
  const float* obs_fc0_w  = (const float*)d_in[18];
  const float* obs_fc0_b  = (const float*)d_in[19];
  const float* obs_n_s    = (const float*)d_in[20];
  const float* obs_out_w  = (const float*)d_in[21];
  const float* obs_out_b  = (const float*)d_in[22];

  float*  out = (float*)d_out;
  float*  ws  = (float*)d_ws;
  ushort* wsU = (ushort*)d_ws;
  ushort* xbp = (ushort*)(ws + F_XB);
  float*  xh  = ws + F_XH;
  ushort* xhp = (ushort*)(ws + F_XH);
  ushort* hbp = (ushort*)(ws + F_HB);
  float*  part = xh;

  hipLaunchKernelGGL(k_prep, dim3(2176), dim3(256), 0, stream,
                     hid0_k, gru_k, in0_w, in1_w, obs_fc0_w, obs_out_w, wsU);
  hipLaunchKernelGGL(k_x2, dim3(256), dim3(256), 0, stream,
                     action, in2_w, in2_b, n2_s, xbp);
  hipLaunchKernelGGL(k_gemm256, dim3(384), dim3(512), 0, stream,
                     0, deter, stoch, out + OFF_DETER, embed, wsU, part);
  hipLaunchKernelGGL(k_comb_in, dim3(2048), dim3(256), 0, stream,
                     part, in0_b, n0_s, in1_b, n1_s, xbp);
  hipLaunchKernelGGL(k_hid0m, dim3(512), dim3(512), 0, stream,
                     deter, xbp, wsU, hid0_b, xh);
  hipLaunchKernelGGL(k_rmsnorm2048, dim3(4096), dim3(256), 0, stream, xh, hidn_s);
  hipLaunchKernelGGL(k_grum, dim3(2048), dim3(512), 0, stream,
                     xhp, wsU, gru_b, deter, out + OFF_DETER);
  hipLaunchKernelGGL(k_gemm256, dim3(256), dim3(512), 0, stream,
                     1, deter, stoch, out + OFF_DETER, embed, wsU, part);
  hipLaunchKernelGGL(k_comb4, dim3(1024), dim3(256), 0, stream,
                     part, obs_fc0_b, obs_n_s, hbp);
  hipLaunchKernelGGL(k_obsoutm, dim3(128), dim3(512), 0, stream,
                     hbp, wsU, obs_out_b, out + OFF_LOGIT);
  hipLaunchKernelGGL(k_argmax, dim3(1024), dim3(256), 0, stream,
                     out + OFF_LOGIT, out + OFF_STOCH);
}

// Round 15
// 215.384 us; speedup vs baseline: 1.1618x; 1.1618x over previous
//
#include <hip/hip_runtime.h>
#include <cmath>

// ---------------- problem constants ----------------
constexpr int BATCH = 4096;
constexpr float EPSN = 1e-4f;

// d_out layout (floats): [new_stoch | new_deter | logit]
constexpr int OFF_STOCH = 0;
constexpr int OFF_DETER = BATCH * 512;
constexpr int OFF_LOGIT = OFF_DETER + BATCH * 2048;

typedef unsigned short ushort;
typedef __attribute__((ext_vector_type(4))) float f32x4;
typedef __attribute__((ext_vector_type(8))) short s16x8;
struct us4 { ushort x, y, z, w; };

// ---------------- ws layout (PROVEN 61.5 MiB budget — do not exceed) ----------------
constexpr size_t U_WHH = 0;                      // hid hi  [g] 256n x 1024k (NK=32)
constexpr size_t U_WHL = U_WHH + 2097152;
constexpr size_t U_WGH = U_WHL + 2097152;        // gru hi  [g*4+nc] 192n x 256k (NK=8)
constexpr size_t U_WGL = U_WGH + 1572864;
constexpr size_t U_WFH = U_WGL + 1572864;        // obs_fc0 hi 256n x 3072k (NK=96)
constexpr size_t U_WFL = U_WFH + 786432;
constexpr size_t U_WOH = U_WFL + 786432;         // obs_out hi 512n x 256k (NK=8)
constexpr size_t U_WOL = U_WOH + 131072;
constexpr size_t U_PEND = U_WOL + 131072;        // 9,175,040 ushorts
constexpr size_t F_XB = U_PEND / 2;              // xb: packed [4096][768h|768l] bf16
constexpr size_t F_XH = F_XB + 3145728;          // xh: f32 yh then packed [2048h|2048l]/row
constexpr size_t U_X0H = (F_XH + 6291456) * 2;   // transient in0_w 256n x 2048k (NK=64)
constexpr size_t U_X0L = U_X0H + 524288;
constexpr size_t U_X1H = U_X0L + 524288;         // in1_w 256n x 512k (NK=16)
constexpr size_t U_X1L = U_X1H + 131072;
constexpr size_t F_HB = F_XH + 4194304;          // hb packed [4096][256h|256l]

#define DINLINE __device__ __forceinline__

DINLINE float sigm(float x)  { return 1.0f / (1.0f + expf(-x)); }
DINLINE float siluf(float x) { return x / (1.0f + expf(-x)); }

DINLINE float4 ld4(const float* p) { return *reinterpret_cast<const float4*>(p); }
DINLINE void st4(float* p, float4 v) { *reinterpret_cast<float4*>(p) = v; }

DINLINE ushort f2bf(float x) {  // RNE f32->bf16 bits
  unsigned u = __float_as_uint(x);
  unsigned r = u + 0x7fffu + ((u >> 16) & 1u);
  return (ushort)(r >> 16);
}
DINLINE float bf2f(ushort h) { return __uint_as_float(((unsigned)h) << 16); }

DINLINE void cp16g(void* lds, const void* g) {
  __builtin_amdgcn_global_load_lds(
      (const __attribute__((address_space(1))) unsigned int*)g,
      (__attribute__((address_space(3))) unsigned int*)lds, 16, 0, 0);
}

DINLINE f32x4 mfma16(s16x8 a, s16x8 b, f32x4 c) {
  return __builtin_amdgcn_mfma_f32_16x16x32_bf16(a, b, c, 0, 0, 0);
}

// XOR-swizzled LDS byte address for [row][64B of k] bf16 tiles (validated round 6).
DINLINE int swz_addr(int row, int kb0) {
  return (row * 64 + kb0) ^ ((row & 7) << 4);
}
DINLINE void dec_swz(int D, int& row, int& kb) {
  int r2 = (D >> 8) & 1;
  int r0 = ((D >> 6) & 1) ^ r2;
  row = ((D >> 7) << 1) | r0;
  kb = (D & 48) ^ ((row & 3) << 4);
}

DINLINE void split2(float x, ushort& h, ushort& l) {
  h = f2bf(x);
  l = f2bf(x - bf2f(h));
}

DINLINE size_t frag_idx(int n, int k, int NK) {
  return ((size_t)((n >> 4) * NK + (k >> 5)) * 64 + ((k >> 3) & 3) * 16 + (n & 15)) * 8 + (k & 7);
}

DINLINE float4 rms_silu4(float v0, float v1, float v2, float v3, float4 s4) {
  float ss = v0 * v0 + v1 * v1 + v2 * v2 + v3 * v3;
#pragma unroll
  for (int off = 32; off; off >>= 1) ss += __shfl_xor(ss, off);
  float inv = 1.0f / sqrtf(ss * (1.0f / 256.0f) + EPSN);
  float4 o;
  o.x = siluf(v0 * inv * s4.x); o.y = siluf(v1 * inv * s4.y);
  o.z = siluf(v2 * inv * s4.z); o.w = siluf(v3 * inv * s4.w);
  return o;
}

// ---------------- kernel 1: weight prep (fragment-major, unchanged r11) ----------------
__global__ __launch_bounds__(256) void k_prep(
    const float* __restrict__ hk, const float* __restrict__ gk,
    const float* __restrict__ w0, const float* __restrict__ w1,
    const float* __restrict__ wf, const float* __restrict__ wo,
    ushort* __restrict__ wsU) {
  __shared__ float L[64 * 65];
  const int bid = blockIdx.x, tid = threadIdx.x;
  if (bid < 1792) {
    int t = bid * 256 + tid;
    if (t < 262144) {
      int o = t >> 10, i = t & 1023;
      const float* src = hk + (size_t)t * 8;
      float4 v0 = ld4(src), v1 = ld4(src + 4);
      float vv[8] = {v0.x, v0.y, v0.z, v0.w, v1.x, v1.y, v1.z, v1.w};
      size_t fi = frag_idx(o, i, 32);
#pragma unroll
      for (int g2 = 0; g2 < 8; ++g2) {
        ushort h, l; split2(vv[g2], h, l);
        wsU[U_WHH + (size_t)g2 * 262144 + fi] = h;
        wsU[U_WHL + (size_t)g2 * 262144 + fi] = l;
      }
    } else {
      int e = t - 262144;
      int o = e >> 8, i = e & 255;
      const float* src = gk + (size_t)e * 8;
      float4 v0 = ld4(src), v1 = ld4(src + 4);
      float vv[8] = {v0.x, v0.y, v0.z, v0.w, v1.x, v1.y, v1.z, v1.w};
      int gate = o >> 8, nc = (o >> 6) & 3, srow = gate * 64 + (o & 63);
      size_t fi = frag_idx(srow, i, 8);
#pragma unroll
      for (int g2 = 0; g2 < 8; ++g2) {
        ushort h, l; split2(vv[g2], h, l);
        size_t pb = (size_t)(g2 * 4 + nc) * 49152;
        wsU[U_WGH + pb + fi] = h;
        wsU[U_WGL + pb + fi] = l;
      }
    }
    return;
  }
  int t = bid - 1792;
  const float* src; ushort* dh; ushort* dl; int K, N;
  if (t < 128)      { src = w0; dh = wsU + U_X0H; dl = wsU + U_X0L; K = 2048; N = 256; }
  else if (t < 160) { t -= 128; src = w1; dh = wsU + U_X1H; dl = wsU + U_X1L; K = 512;  N = 256; }
  else if (t < 352) { t -= 160; src = wf; dh = wsU + U_WFH; dl = wsU + U_WFL; K = 3072; N = 256; }
  else              { t -= 352; src = wo; dh = wsU + U_WOH; dl = wsU + U_WOL; K = 256;  N = 512; }
  const int NK = K / 32;
  const int ntiles = N / 64;
  const int k0 = (t / ntiles) * 64, n0 = (t % ntiles) * 64;
#pragma unroll
  for (int q = 0; q < 4; ++q) {
    int row = q * 16 + (tid >> 4), col = (tid & 15) * 4;
    float4 v = ld4(src + (size_t)(k0 + row) * N + n0 + col);
    L[row * 65 + col]     = v.x;
    L[row * 65 + col + 1] = v.y;
    L[row * 65 + col + 2] = v.z;
    L[row * 65 + col + 3] = v.w;
  }
  __syncthreads();
  const int nl = tid >> 2, kc = (tid & 3) * 16;
  const int ng = n0 + nl;
  s16x8 h0, h1, l0v, l1v;
#pragma unroll
  for (int j = 0; j < 16; ++j) {
    ushort h, l; split2(L[(kc + j) * 65 + nl], h, l);
    if (j < 8) { h0[j] = (short)h; l0v[j] = (short)l; }
    else       { h1[j - 8] = (short)h; l1v[j - 8] = (short)l; }
  }
  size_t fa = frag_idx(ng, k0 + kc, NK);
  size_t fb = frag_idx(ng, k0 + kc + 8, NK);
  *(s16x8*)(dh + fa) = h0;
  *(s16x8*)(dh + fb) = h1;
  *(s16x8*)(dl + fa) = l0v;
  *(s16x8*)(dl + fb) = l1v;
}

// ---------------- unified MFMA GEMM: A via LDS, B post-MFMA (r13 placement) ----------------
__global__ __launch_bounds__(512) void k_gemm256(
    int mode,
    const float* __restrict__ deter, const float* __restrict__ stoch,
    const float* __restrict__ newdet, const float* __restrict__ embed,
    const ushort* __restrict__ wsU, float* __restrict__ part) {
  __shared__ ushort Ah[2][64 * 32], Al[2][64 * 32];
  const int tid = threadIdx.x, lane = tid & 63, wv = tid >> 6;
  const int wr = wv >> 2, wc = wv & 3;
  const int bid = blockIdx.x;
  constexpr size_t PL0 = (size_t)4096 * 512;

  const float* A0; const float* A1 = nullptr;
  int lda0, lda1 = 0, ksw = 1 << 30;
  const ushort* wFh; const ushort* wFl;
  int NKt, kch0, kbase, KT, m0, dstride, dcol;
  float* dst;

  if (mode == 0) {
    if (bid < 256) {
      int ks = bid & 3; m0 = (bid >> 2) * 64; kbase = ks * 512; KT = 16;
      A0 = deter; lda0 = 2048;
      wFh = wsU + U_X0H; wFl = wsU + U_X0L; NKt = 64; kch0 = ks * 16;
      dst = part + (size_t)(ks >> 1) * PL0; dstride = 512; dcol = (ks & 1) * 256;
    } else {
      int b = bid - 256; int ks = b & 1; m0 = (b >> 1) * 64; kbase = ks * 256; KT = 8;
      A0 = stoch; lda0 = 512;
      wFh = wsU + U_X1H; wFl = wsU + U_X1L; NKt = 16; kch0 = ks * 8;
      dst = part + 2 * PL0; dstride = 512; dcol = ks * 256;
    }
  } else {
    int ks = bid & 3; m0 = (bid >> 2) * 64; kbase = ks * 768; KT = 24;
    A0 = newdet; lda0 = 2048; A1 = embed; lda1 = 1024; ksw = 2048;
    wFh = wsU + U_WFH; wFl = wsU + U_WFL; NKt = 96; kch0 = ks * 24;
    dst = part + (size_t)ks * 4096 * 256; dstride = 256; dcol = 0;
  }

  const int arow = tid >> 2, akq = (tid & 3) * 8;
  const int abyte = swz_addr(arow, (tid & 3) * 16);
  float av[8];
  s16x8 bh[4], bl[4];

  const f32x4 z4 = {0.f, 0.f, 0.f, 0.f};
  f32x4 acc[2][4];
#pragma unroll
  for (int i = 0; i < 2; ++i)
#pragma unroll
    for (int j = 0; j < 4; ++j) acc[i][j] = z4;

#define U_LOADA(kt) \
  if (tid < 256) { \
    int kg = kbase + (kt) * 32 + akq; \
    const float* p = (kg < ksw) ? A0 + (size_t)(m0 + arow) * lda0 + kg \
                                : A1 + (size_t)(m0 + arow) * lda1 + (kg - ksw); \
    float4 u_ = ld4(p), w_ = ld4(p + 4); \
    av[0] = u_.x; av[1] = u_.y; av[2] = u_.z; av[3] = u_.w; \
    av[4] = w_.x; av[5] = w_.y; av[6] = w_.z; av[7] = w_.w; \
  }
#define U_WRITEA(buf) \
  if (tid < 256) { \
    s16x8 h8, l8; \
    _Pragma("unroll") \
    for (int j = 0; j < 8; ++j) { \
      ushort h_, l_; split2(av[j], h_, l_); \
      h8[j] = (short)h_; l8[j] = (short)l_; \
    } \
    *(s16x8*)((char*)Ah[buf] + abyte) = h8; \
    *(s16x8*)((char*)Al[buf] + abyte) = l8; \
  }
#define U_LOADB(kt) { \
    _Pragma("unroll") \
    for (int nf = 0; nf < 4; ++nf) { \
      size_t fo = ((size_t)((wc * 4 + nf) * NKt + kch0 + (kt)) * 64 + lane) * 8; \
      bh[nf] = *(const s16x8*)(wFh + fo); \
      bl[nf] = *(const s16x8*)(wFl + fo); \
    } }

  U_LOADA(0);
  U_WRITEA(0);
  U_LOADB(0);
  __syncthreads();
  int cur = 0;
  for (int t = 0; t < KT; ++t) {
    if (t + 1 < KT) { U_LOADA(t + 1); }
    const int k16 = (lane >> 4) * 16;
    s16x8 afh[2], afl[2];
#pragma unroll
    for (int mf = 0; mf < 2; ++mf) {
      int by = swz_addr(wr * 32 + mf * 16 + (lane & 15), k16);
      afh[mf] = *(const s16x8*)((const char*)Ah[cur] + by);
      afl[mf] = *(const s16x8*)((const char*)Al[cur] + by);
    }
#pragma unroll
    for (int nf = 0; nf < 4; ++nf) {
#pragma unroll
      for (int mf = 0; mf < 2; ++mf) {
        acc[mf][nf] = mfma16(afh[mf], bh[nf], acc[mf][nf]);
        acc[mf][nf] = mfma16(afh[mf], bl[nf], acc[mf][nf]);
        acc[mf][nf] = mfma16(afl[mf], bh[nf], acc[mf][nf]);
      }
    }
    if (t + 1 < KT) { U_LOADB(t + 1); U_WRITEA(cur ^ 1); }
    __syncthreads();
    cur ^= 1;
  }
#undef U_LOADA
#undef U_WRITEA
#undef U_LOADB
#pragma unroll
  for (int mf = 0; mf < 2; ++mf) {
    int rbase = m0 + wr * 32 + mf * 16 + ((lane >> 4) << 2);
#pragma unroll
    for (int nf = 0; nf < 4; ++nf) {
      int col = dcol + wc * 64 + nf * 16 + (lane & 15);
#pragma unroll
      for (int r = 0; r < 4; ++r)
        dst[(size_t)(rbase + r) * dstride + col] = acc[mf][nf][r];
    }
  }
}

// ---------------- x2: K=17 projection, 256 blocks x 256 threads ----------------
__global__ __launch_bounds__(256) void k_x2(
    const float* __restrict__ action, const float* __restrict__ w2,
    const float* __restrict__ b2, const float* __restrict__ s2,
    ushort* __restrict__ xbp) {
  __shared__ float W2s[17 * 256];
  __shared__ float A2s[16 * 20];
  const int tid = threadIdx.x, tx = tid & 63, wv = tid >> 6;
  const int m0 = blockIdx.x * 16;
  for (int e = tid; e < 17 * 256; e += 256) W2s[e] = w2[e];
  for (int e = tid; e < 272; e += 256) {
    int r = e / 17, c = e % 17;
    float a = action[(size_t)(m0 + r) * 17 + c];
    float m = fabsf(a);
    A2s[r * 20 + c] = a / (m > 1.f ? m : 1.f);
  }
  __syncthreads();
  float4 acc2[4];
#pragma unroll
  for (int r = 0; r < 4; ++r) acc2[r] = make_float4(0.f, 0.f, 0.f, 0.f);
#pragma unroll
  for (int k = 0; k < 17; ++k) {
    float4 w4 = ld4(W2s + k * 256 + tx * 4);
#pragma unroll
    for (int r = 0; r < 4; ++r) {
      float av = A2s[(wv * 4 + r) * 20 + k];
      acc2[r].x = fmaf(av, w4.x, acc2[r].x);
      acc2[r].y = fmaf(av, w4.y, acc2[r].y);
      acc2[r].z = fmaf(av, w4.z, acc2[r].z);
      acc2[r].w = fmaf(av, w4.w, acc2[r].w);
    }
  }
  float4 b4 = ld4(b2 + tx * 4);
  float4 s4 = ld4(s2 + tx * 4);
#pragma unroll
  for (int r = 0; r < 4; ++r) {
    float4 o = rms_silu4(acc2[r].x + b4.x, acc2[r].y + b4.y,
                         acc2[r].z + b4.z, acc2[r].w + b4.w, s4);
    us4 h4, l4;
    split2(o.x, h4.x, l4.x); split2(o.y, h4.y, l4.y);
    split2(o.z, h4.z, l4.z); split2(o.w, h4.w, l4.w);
    size_t rb = (size_t)(m0 + wv * 4 + r) * 1536;
    *(us4*)(xbp + rb + 512 + tx * 4) = h4;
    *(us4*)(xbp + rb + 768 + 512 + tx * 4) = l4;
  }
}

// ---------------- combine: x0 | x1 + bias + rmsnorm + silu -> packed xb ----------------
__global__ __launch_bounds__(256) void k_comb_in(
    const float* __restrict__ part,
    const float* __restrict__ b0, const float* __restrict__ s0,
    const float* __restrict__ b1, const float* __restrict__ s1,
    ushort* __restrict__ xbp) {
  const int tid = threadIdx.x, tx = tid & 63, wv = tid >> 6;
  const size_t row = blockIdx.x * 2 + (wv >> 1);
  const int half = wv & 1;
  constexpr size_t PL = (size_t)4096 * 512;
  float4 v = make_float4(0.f, 0.f, 0.f, 0.f);
  if (half == 0) {
#pragma unroll
    for (int p = 0; p < 2; ++p) {
      const float* s = part + p * PL + row * 512 + tx * 4;
      float4 a = ld4(s), b = ld4(s + 256);
      v.x += a.x + b.x; v.y += a.y + b.y; v.z += a.z + b.z; v.w += a.w + b.w;
    }
  } else {
    const float* s = part + 2 * PL + row * 512 + tx * 4;
    float4 a = ld4(s), b = ld4(s + 256);
    v.x = a.x + b.x; v.y = a.y + b.y; v.z = a.z + b.z; v.w = a.w + b.w;
  }
  const float* bp = half ? b1 : b0;
  const float* sp = half ? s1 : s0;
  float4 b4 = ld4(bp + tx * 4);
  float4 s4 = ld4(sp + tx * 4);
  float4 o = rms_silu4(v.x + b4.x, v.y + b4.y, v.z + b4.z, v.w + b4.w, s4);
  us4 h4, l4;
  split2(o.x, h4.x, l4.x); split2(o.y, h4.y, l4.y);
  split2(o.z, h4.z, l4.z); split2(o.w, h4.w, l4.w);
  *(us4*)(xbp + row * 1536 + half * 256 + tx * 4) = h4;
  *(us4*)(xbp + row * 1536 + 768 + half * 256 + tx * 4) = l4;
}

// ---------------- combine p=4 (obsfc0) -> packed hb ----------------
__global__ __launch_bounds__(256) void k_comb4(
    const float* __restrict__ part, const float* __restrict__ bias,
    const float* __restrict__ scale, ushort* __restrict__ hbp) {
  const int tid = threadIdx.x, tx = tid & 63, wv = tid >> 6;
  const size_t row = blockIdx.x * 4 + wv;
  float4 v = make_float4(0.f, 0.f, 0.f, 0.f);
#pragma unroll
  for (int ks = 0; ks < 4; ++ks) {
    float4 t = ld4(part + (size_t)ks * 4096 * 256 + row * 256 + tx * 4);
    v.x += t.x; v.y += t.y; v.z += t.z; v.w += t.w;
  }
  float4 b4 = ld4(bias + tx * 4);
  float4 s4 = ld4(scale + tx * 4);
  float4 o = rms_silu4(v.x + b4.x, v.y + b4.y, v.z + b4.z, v.w + b4.w, s4);
  us4 h4, l4;
  split2(o.x, h4.x, l4.x); split2(o.y, h4.y, l4.y);
  split2(o.z, h4.z, l4.z); split2(o.w, h4.w, l4.w);
  *(us4*)(hbp + row * 512 + tx * 4) = h4;
  *(us4*)(hbp + row * 512 + 256 + tx * 4) = l4;
}

// ---------------- hid0: A LDS, B post-MFMA (r13 placement) ----------------
__global__ __launch_bounds__(512) void k_hid0m(
    const float* __restrict__ deter, const ushort* __restrict__ xbp,
    const ushort* __restrict__ wsU,
    const float* __restrict__ hbias, float* __restrict__ yh) {
  __shared__ ushort Ah[2][64 * 32], Al[2][64 * 32];
  const int tid = threadIdx.x, lane = tid & 63, wv = tid >> 6;
  const int wr = wv >> 2, wc = wv & 3;
  const int g = blockIdx.x & 7;
  const int m0 = (int)(blockIdx.x >> 3) * 64;

  const ushort* whFh = wsU + U_WHH + (size_t)g * 262144;
  const ushort* whFl = wsU + U_WHL + (size_t)g * 262144;
  const char* xbB = (const char*)xbp;

  const int arow = tid >> 2, akq = (tid & 3) * 8;
  const int abyte = swz_addr(arow, (tid & 3) * 16);
  int an0, akb;
  dec_swz(tid * 16, an0, akb);
  float av[8];
  s16x8 bh[4], bl[4];

  const f32x4 z4 = {0.f, 0.f, 0.f, 0.f};
  f32x4 acc[2][4];
#pragma unroll
  for (int i = 0; i < 2; ++i)
#pragma unroll
    for (int j = 0; j < 4; ++j) acc[i][j] = z4;

#define H_LOADA_DET(kt) \
  if (tid < 256) { \
    const float* p = deter + (size_t)(m0 + arow) * 2048 + g * 256 + (kt) * 32 + akq; \
    float4 u_ = ld4(p), w_ = ld4(p + 4); \
    av[0] = u_.x; av[1] = u_.y; av[2] = u_.z; av[3] = u_.w; \
    av[4] = w_.x; av[5] = w_.y; av[6] = w_.z; av[7] = w_.w; \
  }
#define H_WRITEA(buf) \
  if (tid < 256) { \
    s16x8 h8, l8; \
    _Pragma("unroll") \
    for (int j = 0; j < 8; ++j) { \
      ushort h_, l_; split2(av[j], h_, l_); \
      h8[j] = (short)h_; l8[j] = (short)l_; \
    } \
    *(s16x8*)((char*)Ah[buf] + abyte) = h8; \
    *(s16x8*)((char*)Al[buf] + abyte) = l8; \
  }
#define H_ISSUEA(buf, kt) \
  if (tid < 256) { \
    size_t rb = (size_t)(m0 + an0) * 3072; \
    int co = ((kt) * 32 - 256) * 2 + akb; \
    cp16g((char*)Ah[buf] + tid * 16, xbB + rb + co); \
    cp16g((char*)Al[buf] + tid * 16, xbB + rb + 1536 + co); \
  }
#define H_LOADB(kt) { \
    _Pragma("unroll") \
    for (int nf = 0; nf < 4; ++nf) { \
      size_t fo = ((size_t)((wc * 4 + nf) * 32 + (kt)) * 64 + lane) * 8; \
      bh[nf] = *(const s16x8*)(whFh + fo); \
      bl[nf] = *(const s16x8*)(whFl + fo); \
    } }

  H_LOADA_DET(0);
  H_WRITEA(0);
  H_LOADB(0);
  __syncthreads();
  int cur = 0;
  for (int t = 0; t < 32; ++t) {
    const bool pf = (t + 1 < 32);
    const bool det = (t + 1 < 8);
    if (pf) {
      if (det) { H_LOADA_DET(t + 1); }
      else     { H_ISSUEA(cur ^ 1, t + 1); }
    }
    const int k16 = (lane >> 4) * 16;
    s16x8 afh[2], afl[2];
#pragma unroll
    for (int mf = 0; mf < 2; ++mf) {
      int by = swz_addr(wr * 32 + mf * 16 + (lane & 15), k16);
      afh[mf] = *(const s16x8*)((const char*)Ah[cur] + by);
      afl[mf] = *(const s16x8*)((const char*)Al[cur] + by);
    }
#pragma unroll
    for (int nf = 0; nf < 4; ++nf) {
#pragma unroll
      for (int mf = 0; mf < 2; ++mf) {
        acc[mf][nf] = mfma16(afh[mf], bh[nf], acc[mf][nf]);
        acc[mf][nf] = mfma16(afh[mf], bl[nf], acc[mf][nf]);
        acc[mf][nf] = mfma16(afl[mf], bh[nf], acc[mf][nf]);
      }
    }
    if (pf) { H_LOADB(t + 1); }
    if (pf && det) { H_WRITEA(cur ^ 1); }
    __syncthreads();
    cur ^= 1;
  }
#undef H_LOADA_DET
#undef H_WRITEA
#undef H_ISSUEA
#undef H_LOADB
#pragma unroll
  for (int mf = 0; mf < 2; ++mf) {
    int rbase = m0 + wr * 32 + mf * 16 + ((lane >> 4) << 2);
#pragma unroll
    for (int nf = 0; nf < 4; ++nf) {
      int col = wc * 64 + nf * 16 + (lane & 15);
      float b = hbias[g * 256 + col];
#pragma unroll
      for (int r = 0; r < 4; ++r)
        yh[(size_t)(rbase + r) * 2048 + g * 256 + col] = acc[mf][nf][r] + b;
    }
  }
}

// ---------------- rmsnorm(2048)+silu -> in-place packed [2048h|2048l] bf16 ----------------
__global__ __launch_bounds__(256) void k_rmsnorm2048(
    float* __restrict__ xh, const float* __restrict__ scale) {
  const int b = blockIdx.x, tid = threadIdx.x;
  float* row = xh + (size_t)b * 2048;
  float4 v0 = ld4(row + tid * 8);
  float4 v1 = ld4(row + tid * 8 + 4);
  float ss = v0.x * v0.x + v0.y * v0.y + v0.z * v0.z + v0.w * v0.w +
             v1.x * v1.x + v1.y * v1.y + v1.z * v1.z + v1.w * v1.w;
#pragma unroll
  for (int off = 32; off; off >>= 1) ss += __shfl_xor(ss, off);
  __shared__ float wsum[4];
  if ((tid & 63) == 0) wsum[tid >> 6] = ss;
  __syncthreads();
  float tot = wsum[0] + wsum[1] + wsum[2] + wsum[3];
  float inv = 1.0f / sqrtf(tot * (1.0f / 2048.0f) + EPSN);
  float4 sc0 = ld4(scale + tid * 8);
  float4 sc1 = ld4(scale + tid * 8 + 4);
  float o[8];
  o[0] = siluf(v0.x * inv * sc0.x); o[1] = siluf(v0.y * inv * sc0.y);
  o[2] = siluf(v0.z * inv * sc0.z); o[3] = siluf(v0.w * inv * sc0.w);
  o[4] = siluf(v1.x * inv * sc1.x); o[5] = siluf(v1.y * inv * sc1.y);
  o[6] = siluf(v1.z * inv * sc1.z); o[7] = siluf(v1.w * inv * sc1.w);
  s16x8 h8, l8;
#pragma unroll
  for (int j = 0; j < 8; ++j) {
    ushort h, l; split2(o[j], h, l);
    h8[j] = (short)h; l8[j] = (short)l;
  }
  ushort* rp = (ushort*)row;
  *(s16x8*)(rp + tid * 8) = h8;
  *(s16x8*)(rp + 2048 + tid * 8) = l8;
}

// ---------------- gru: BM=64, stage ALL A once, barrier-free main loop (r14) ----------------
__global__ __launch_bounds__(512) void k_grum(
    const ushort* __restrict__ xhp, const ushort* __restrict__ wsU,
    const float* __restrict__ gb, const float* __restrict__ deter,
    float* __restrict__ newdet) {
  __shared__ ushort Ah[8][64 * 32], Al[8][64 * 32];   // 32KB + 32KB
  const int tid = threadIdx.x, lane = tid & 63, wv = tid >> 6;
  const int wr = wv >> 2, wc = wv & 3;
  const int g = blockIdx.x & 7;
  const int nc = (int)(blockIdx.x >> 3) & 3;
  const int m0 = (int)(blockIdx.x >> 5) * 64;

  const ushort* wgFh = wsU + U_WGH + (size_t)(g * 4 + nc) * 49152;
  const ushort* wgFl = wsU + U_WGL + (size_t)(g * 4 + nc) * 49152;
  const char* xhB = (const char*)xhp;

#pragma unroll
  for (int q = 0; q < 4; ++q) {
    int lin = q * 8192 + tid * 16;
    int chunk = lin >> 12;
    int within = lin & 4095;
    int row, kb;
    dec_swz(within, row, kb);
    size_t src = (size_t)(m0 + row) * 8192 + (size_t)(g * 256 + chunk * 32) * 2 + kb;
    cp16g((char*)Ah + lin, xhB + src);
    cp16g((char*)Al + lin, xhB + src + 4096);
  }
  __syncthreads();   // ONE barrier; main loop barrier-free

  const f32x4 z4 = {0.f, 0.f, 0.f, 0.f};
  f32x4 acc[2][3];
#pragma unroll
  for (int i = 0; i < 2; ++i)
#pragma unroll
    for (int j = 0; j < 3; ++j) acc[i][j] = z4;

#pragma unroll
  for (int t = 0; t < 8; ++t) {
    s16x8 bh[3], bl[3];
#pragma unroll
    for (int gt = 0; gt < 3; ++gt) {
      size_t fo = ((size_t)((gt * 4 + wc) * 8 + t) * 64 + lane) * 8;
      bh[gt] = *(const s16x8*)(wgFh + fo);
      bl[gt] = *(const s16x8*)(wgFl + fo);
    }
    const int k16 = (lane >> 4) * 16;
    s16x8 afh[2], afl[2];
#pragma unroll
    for (int mf = 0; mf < 2; ++mf) {
      int by = swz_addr(wr * 32 + mf * 16 + (lane & 15), k16);
      afh[mf] = *(const s16x8*)((const char*)Ah[t] + by);
      afl[mf] = *(const s16x8*)((const char*)Al[t] + by);
    }
#pragma unroll
    for (int gt = 0; gt < 3; ++gt) {
#pragma unroll
      for (int mf = 0; mf < 2; ++mf) {
        acc[mf][gt] = mfma16(afh[mf], bh[gt], acc[mf][gt]);
        acc[mf][gt] = mfma16(afh[mf], bl[gt], acc[mf][gt]);
        acc[mf][gt] = mfma16(afl[mf], bh[gt], acc[mf][gt]);
      }
    }
  }
  const int col = nc * 64 + wc * 16 + (lane & 15);
  const float br = gb[g * 768 + col];
  const float bc = gb[g * 768 + 256 + col];
  const float bu = gb[g * 768 + 512 + col];
#pragma unroll
  for (int mf = 0; mf < 2; ++mf) {
    int rbase = m0 + wr * 32 + mf * 16 + ((lane >> 4) << 2);
#pragma unroll
    for (int r = 0; r < 4; ++r) {
      int row = rbase + r;
      float rr = sigm(acc[mf][0][r] + br);
      float cc = acc[mf][1][r] + bc;
      float uu = sigm(acc[mf][2][r] + bu - 1.0f);
      float d = deter[(size_t)row * 2048 + g * 256 + col];
      newdet[(size_t)row * 2048 + g * 256 + col] =
          uu * tanhf(rr * cc) + (1.0f - uu) * d;
    }
  }
}

// ---------------- obs_out: A cp16, B post-MFMA (r13 placement) ----------------
__global__ __launch_bounds__(512) void k_obsoutm(
    const ushort* __restrict__ hbp, const ushort* __restrict__ wsU,
    const float* __restrict__ ob, float* __restrict__ logit) {
  __shared__ ushort Ah[2][64 * 32], Al[2][64 * 32];
  const int tid = threadIdx.x, lane = tid & 63, wv = tid >> 6;
  const int wr = wv >> 2, wc = wv & 3;
  const int half = blockIdx.x & 1;
  const int m0 = (int)(blockIdx.x >> 1) * 64;

  const ushort* woFh = wsU + U_WOH;
  const ushort* woFl = wsU + U_WOL;
  const char* hbB = (const char*)hbp;
  int an0, akb;
  dec_swz(tid * 16, an0, akb);
  s16x8 bh[4], bl[4];

  const f32x4 z4 = {0.f, 0.f, 0.f, 0.f};
  f32x4 acc[2][4];
#pragma unroll
  for (int i = 0; i < 2; ++i)
#pragma unroll
    for (int j = 0; j < 4; ++j) acc[i][j] = z4;

#define O_ISSUEA(buf, kt) \
  if (tid < 256) { \
    size_t rb = (size_t)(m0 + an0) * 1024; \
    int co = (kt) * 64 + akb; \
    cp16g((char*)Ah[buf] + tid * 16, hbB + rb + co); \
    cp16g((char*)Al[buf] + tid * 16, hbB + rb + 512 + co); \
  }
#define O_LOADB(kt) { \
    _Pragma("unroll") \
    for (int nf = 0; nf < 4; ++nf) { \
      size_t fo = ((size_t)((half * 16 + wc * 4 + nf) * 8 + (kt)) * 64 + lane) * 8; \
      bh[nf] = *(const s16x8*)(woFh + fo); \
      bl[nf] = *(const s16x8*)(woFl + fo); \
    } }

  O_ISSUEA(0, 0);
  O_LOADB(0);
  __syncthreads();
  int cur = 0;
  for (int t = 0; t < 8; ++t) {
    if (t + 1 < 8) { O_ISSUEA(cur ^ 1, t + 1); }
    const int k16 = (lane >> 4) * 16;
    s16x8 afh[2], afl[2];
#pragma unroll
    for (int mf = 0; mf < 2; ++mf) {
      int by = swz_addr(wr * 32 + mf * 16 + (lane & 15), k16);
      afh[mf] = *(const s16x8*)((const char*)Ah[cur] + by);
      afl[mf] = *(const s16x8*)((const char*)Al[cur] + by);
    }
#pragma unroll
    for (int nf = 0; nf < 4; ++nf) {
#pragma unroll
      for (int mf = 0; mf < 2; ++mf) {
        acc[mf][nf] = mfma16(afh[mf], bh[nf], acc[mf][nf]);
        acc[mf][nf] = mfma16(afh[mf], bl[nf], acc[mf][nf]);
        acc[mf][nf] = mfma16(afl[mf], bh[nf], acc[mf][nf]);
      }
    }
    if (t + 1 < 8) { O_LOADB(t + 1); }
    __syncthreads();
    cur ^= 1;
  }
#undef O_ISSUEA
#undef O_LOADB
#pragma unroll
  for (int mf = 0; mf < 2; ++mf) {
    int rbase = m0 + wr * 32 + mf * 16 + ((lane >> 4) << 2);
#pragma unroll
    for (int nf = 0; nf < 4; ++nf) {
      int col = half * 256 + wc * 64 + nf * 16 + (lane & 15);
      float b = ob[col];
#pragma unroll
      for (int r = 0; r < 4; ++r)
        logit[(size_t)(rbase + r) * 512 + col] = acc[mf][nf][r] + b;
    }
  }
}

// ---------------- argmax -> one-hot (first-index ties) ----------------
__global__ __launch_bounds__(256) void k_argmax(
    const float* __restrict__ logit, float* __restrict__ stoch_out) {
  const size_t row = blockIdx.x * 4 + (threadIdx.x >> 6);
  const int lane = threadIdx.x & 63;
  const float* lp = logit + row * 512 + lane * 8;
  float4 a = ld4(lp), b = ld4(lp + 4);
  float v[8] = {a.x, a.y, a.z, a.w, b.x, b.y, b.z, b.w};
  float bv = v[0]; int bi = 0;
#pragma unroll
  for (int j = 1; j < 8; ++j)
    if (v[j] > bv) { bv = v[j]; bi = j; }
  bi += lane * 8;
  float pv = __shfl_xor(bv, 1);
  int   pi = __shfl_xor(bi, 1);
  if (pv > bv || (pv == bv && pi < bi)) { bv = pv; bi = pi; }
  float4 o0, o1;
  int base = lane * 8;
  o0.x = (bi == base + 0) ? 1.f : 0.f;
  o0.y = (bi == base + 1) ? 1.f : 0.f;
  o0.z = (bi == base + 2) ? 1.f : 0.f;
  o0.w = (bi == base + 3) ? 1.f : 0.f;
  o1.x = (bi == base + 4) ? 1.f : 0.f;
  o1.y = (bi == base + 5) ? 1.f : 0.f;
  o1.z = (bi == base + 6) ? 1.f : 0.f;
  o1.w = (bi == base + 7) ? 1.f : 0.f;
  st4(stoch_out + row * 512 + base, o0);
  st4(stoch_out + row * 512 + base + 4, o1);
}

// ---------------- launcher ----------------
extern "C" void kernel_launch(void* const* d_in, const int* in_sizes, int n_in,
                              void* d_out, int out_size, void* d_ws, size_t ws_size,
                              hipStream_t stream) {
  (void)in_sizes; (void)n_in; (void)out_size; (void)ws_size;
  const float* stoch      = (const float*)d_in[0];
  const float* deter      = (const float*)d_in[1];
  const float* action     = (const float*)d_in[2];
  const float* embed      = (const float*)d_in[3];
  const float* in0_w      = (const float*)d_in[4];
  const float* in0_b      = (const float*)d_in[5];
  const float* n0_s       = (const float*)d_in[6];
  const float* in1_w      = (const float*)d_in[7];
  const float* in1_b      = (const float*)d_in[8];
  const float* n1_s       = (const float*)d_in[9];
  const float* in2_w      = (const float*)d_in[10];
  const float* in2_b      = (const float*)d_in[11];
  const float* n2_s       = (const float*)d_in[12];
  const float* hid0_k     = (const float*)d_in[13];
  const float* hid0_b     = (const float*)d_in[14];
  const float* hidn_s     = (const float*)d_in[15];
  const float* gru_k      = (const float*)d_in[16];
  const float* gru_b      = (const float*)d_in[17];
  const float* obs_fc0_w  = (const float*)d_in[18];
  const float* obs_fc0_b  = (const float*)d_in[19];
  const float* obs_n_s    = (const float*)d_in[20];
  const float* obs_out_w  = (const float*)d_in[21];
  const float* obs_out_b  = (const float*)d_in[22];

  float*  out = (float*)d_out;
  float*  ws  = (float*)d_ws;
  ushort* wsU = (ushort*)d_ws;
  ushort* xbp = (ushort*)(ws + F_XB);
  float*  xh  = ws + F_XH;
  ushort* xhp = (ushort*)(ws + F_XH);
  ushort* hbp = (ushort*)(ws + F_HB);
  float*  part = xh;

  hipLaunchKernelGGL(k_prep, dim3(2176), dim3(256), 0, stream,
                     hid0_k, gru_k, in0_w, in1_w, obs_fc0_w, obs_out_w, wsU);
  hipLaunchKernelGGL(k_x2, dim3(256), dim3(256), 0, stream,
                     action, in2_w, in2_b, n2_s, xbp);
  hipLaunchKernelGGL(k_gemm256, dim3(384), dim3(512), 0, stream,
                     0, deter, stoch, out + OFF_DETER, embed, wsU, part);
  hipLaunchKernelGGL(k_comb_in, dim3(2048), dim3(256), 0, stream,
                     part, in0_b, n0_s, in1_b, n1_s, xbp);
  hipLaunchKernelGGL(k_hid0m, dim3(512), dim3(512), 0, stream,
                     deter, xbp, wsU, hid0_b, xh);
  hipLaunchKernelGGL(k_rmsnorm2048, dim3(4096), dim3(256), 0, stream, xh, hidn_s);
  hipLaunchKernelGGL(k_grum, dim3(2048), dim3(512), 0, stream,
                     xhp, wsU, gru_b, deter, out + OFF_DETER);
  hipLaunchKernelGGL(k_gemm256, dim3(256), dim3(512), 0, stream,
                     1, deter, stoch, out + OFF_DETER, embed, wsU, part);
  hipLaunchKernelGGL(k_comb4, dim3(1024), dim3(256), 0, stream,
                     part, obs_fc0_b, obs_n_s, hbp);
  hipLaunchKernelGGL(k_obsoutm, dim3(128), dim3(512), 0, stream,
                     hbp, wsU, obs_out_b, out + OFF_LOGIT);
  hipLaunchKernelGGL(k_argmax, dim3(1024), dim3(256), 0, stream,
                     out + OFF_LOGIT, out + OFF_STOCH);
}